// Round 11
// baseline (541.148 us; speedup 1.0000x reference)
//
#include <hip/hip_runtime.h>

// ---- problem constants ----
#define BB 4
#define SS 1024
#define DD 1024
#define HH 16
#define DHH 64
#define DFF 4096
#define MROWS 4096   // B*S
#define NEG_BIG (-1e30f)
#define LOG2E 1.4426950408889634f
#define SCL_L2E 0.1803368801111244f   // 0.125 * log2(e)

typedef float  f32x4  __attribute__((ext_vector_type(4)));
typedef __bf16 bf16x8 __attribute__((ext_vector_type(8)));
typedef __bf16 bf16x4 __attribute__((ext_vector_type(4)));

#define DEV __device__ __forceinline__

DEV void glds16(const __bf16* g, __bf16* l) {
  __builtin_amdgcn_global_load_lds((__attribute__((address_space(1))) void*)(g),
                                   (__attribute__((address_space(3))) void*)(l),
                                   16, 0, 0);
}

DEV float sanit(float v) {  // NaN/inf absorbing clamp
  return fminf(fmaxf(v, -1e30f), 1e30f);
}

// exact-GELU via A&S 7.1.26 erf (|err|<=1.5e-7, invisible at bf16).
DEV float gelu_f(float v) {
  const float z  = fabsf(v) * 0.70710678118654752f;
  const float t  = __builtin_amdgcn_rcpf(1.f + 0.3275911f * z);
  float poly = ((((1.061405429f * t - 1.453152027f) * t + 1.421413741f) * t
                 - 0.284496736f) * t + 0.254829592f) * t;
  float er = 1.f - poly * __expf(-z * z);
  er = copysignf(er, v);
  return 0.5f * v * (1.f + er);
}

// XCD row-chunk swizzle (T1): hw id w runs on XCD w%8; logical
// idl = (w%8)*(nwg/8) + w/8 gives each XCD a CONTIGUOUS chunk of
// logical blocks; x-major decode -> chunks cover complete rows, so
// each A row-panel is fetched by exactly ONE XCD's L2.
DEV void xcd_rowchunk(int& bx, int& by) {
  const int gx = gridDim.x;
  const int nwg = gx * gridDim.y;
  const int id = blockIdx.x + gx * blockIdx.y;
  const int idl = (id & 7) * (nwg >> 3) + (id >> 3);
  bx = idl % gx;
  by = idl / gx;
}

// ============================================================
// f32 -> bf16 elementwise convert; handles x (4096 blks) then enc
// ============================================================
__global__ __launch_bounds__(256) void cvt2_bf16(
    const float* __restrict__ srcA, __bf16* __restrict__ dstA,
    const float* __restrict__ srcB, __bf16* __restrict__ dstB)
{
  const int bid = blockIdx.x;
  const float* src = (bid < 4096) ? srcA : srcB;
  __bf16* dst      = (bid < 4096) ? dstA : dstB;
  const int idx = ((bid < 4096) ? bid : (bid - 4096)) * 256 + threadIdx.x;
  const f32x4 v = ((const f32x4*)src)[idx];
  bf16x4 o;
#pragma unroll
  for (int i = 0; i < 4; i++) o[i] = (__bf16)v[i];
  ((bf16x4*)dst)[idx] = o;
}

// ============================================================
// LDS-tiled transpose+convert: src f32 [K][N] -> dst bf16 [N][K]
// ============================================================
__global__ __launch_bounds__(256) void wtrans(const float* __restrict__ src,
                                              __bf16* __restrict__ dst,
                                              int K, int N)
{
  __shared__ float t[64][65];
  const int k0 = blockIdx.y * 64, n0 = blockIdx.x * 64;
  const int c = threadIdx.x & 63, r0 = threadIdx.x >> 6;
#pragma unroll
  for (int i = 0; i < 16; i++) {
    const int r = r0 * 16 + i;
    t[r][c] = src[(size_t)(k0 + r) * N + n0 + c];
  }
  __syncthreads();
#pragma unroll
  for (int i = 0; i < 16; i++) {
    const int r = r0 * 16 + i;
    dst[(size_t)(n0 + r) * K + k0 + c] = (__bf16)t[c][r];
  }
}

// ============================================================
// Five 1024x1024 weight transposes in one launch; grid (16, 80)
// ============================================================
__global__ __launch_bounds__(256) void wtrans5(
    const float* __restrict__ s0, const float* __restrict__ s1,
    const float* __restrict__ s2, const float* __restrict__ s3,
    const float* __restrict__ s4,
    __bf16* __restrict__ d0, __bf16* __restrict__ d1,
    __bf16* __restrict__ d2, __bf16* __restrict__ d3,
    __bf16* __restrict__ d4)
{
  __shared__ float t[64][65];
  const int wi = blockIdx.y >> 4;
  const float* src = (wi == 0) ? s0 : (wi == 1) ? s1 : (wi == 2) ? s2
                   : (wi == 3) ? s3 : s4;
  __bf16* dst = (wi == 0) ? d0 : (wi == 1) ? d1 : (wi == 2) ? d2
              : (wi == 3) ? d3 : d4;
  const int k0 = (blockIdx.y & 15) * 64, n0 = blockIdx.x * 64;
  const int c = threadIdx.x & 63, r0 = threadIdx.x >> 6;
#pragma unroll
  for (int i = 0; i < 16; i++) {
    const int r = r0 * 16 + i;
    t[r][c] = src[(size_t)(k0 + r) * 1024 + n0 + c];
  }
  __syncthreads();
#pragma unroll
  for (int i = 0; i < 16; i++) {
    const int r = r0 * 16 + i;
    dst[(size_t)(n0 + r) * 1024 + k0 + c] = (__bf16)t[c][r];
  }
}

// ============================================================
// LDS-tiled V transpose (bf16): dst[bh][d][s]
// ============================================================
__global__ __launch_bounds__(256) void vtrans(const __bf16* __restrict__ src,
                                              int stride, int colMul, int colAdd,
                                              __bf16* __restrict__ dst)
{
  __shared__ __bf16 t[64][66];
  const int bh = blockIdx.y, b = bh >> 4, h = bh & 15;
  const int s0 = blockIdx.x * 64;
  const int c = threadIdx.x & 63, r0 = threadIdx.x >> 6;
  const __bf16* sp = src + (size_t)(b * SS) * stride + h * colMul + colAdd;
#pragma unroll
  for (int i = 0; i < 16; i++) {
    const int s = r0 * 16 + i;
    t[s][c] = sp[(size_t)(s0 + s) * stride + c];
  }
  __syncthreads();
  __bf16* dp = dst + (size_t)bh * 64 * 1024;
#pragma unroll
  for (int i = 0; i < 16; i++) {
    const int d = r0 * 16 + i;
    dp[(size_t)d * 1024 + s0 + c] = t[c][d];
  }
}

// ============================================================
// GEMM 128x256 (4 waves, 2Mx2N; per-wave 64x128 = acc[4][8]):
// 32 MFMA + 12 ds_read per K-iter per wave. 3-stage pipeline,
// vmcnt(12), XCD row-chunk, LDS XOR-swizzle. LDS 72 KB.
// MODE 1: gelu->bf16; 3: qkv Q-col scale; 4: dual bias (merged KV)
// ============================================================
template<int MODE>
__global__ __launch_bounds__(256, 2) void gemm_bt256(
    const __bf16* __restrict__ A, const __bf16* __restrict__ Bt,
    const float* __restrict__ bias, const float* __restrict__ bias2,
    void* __restrict__ Cout, int N, int K)
{
  __shared__ __align__(16) __bf16 As[3][128 * 32];
  __shared__ __align__(16) __bf16 Bs[3][256 * 32];

  int bx, by;
  xcd_rowchunk(bx, by);
  const int bm = by * 128, bn = bx * 256;
  const int tid = threadIdx.x, wid = tid >> 6, lane = tid & 63;
  const int quad = lane >> 4, ln = lane & 15;

  const int sgc = ((lane & 3) ^ ((lane >> 3) & 3)) * 8;
  const __bf16* gA = A  + (size_t)(bm + wid * 32 + (lane >> 2)) * K + sgc;
  const __bf16* gB = Bt + (size_t)(bn + wid * 64 + (lane >> 2)) * K + sgc;
  const int aoff = (wid * 32) * 32;
  const int boff = (wid * 64) * 32;
  const int qsw = (quad ^ ((ln >> 1) & 3)) * 8;   // read-side swizzle

  f32x4 acc[4][8];
#pragma unroll
  for (int i = 0; i < 4; i++)
#pragma unroll
    for (int j = 0; j < 8; j++) acc[i][j] = (f32x4){0.f, 0.f, 0.f, 0.f};

  const int wr = (wid >> 1) * 64, wc = (wid & 1) * 128;

#define G_STAGE(buf, kt) do {                                     \
    const int k0_ = (kt) * 32;                                    \
    glds16(gA + k0_,          &As[buf][aoff]);                    \
    glds16(gA + 16 * K + k0_, &As[buf][aoff + 16 * 32]);          \
    glds16(gB + k0_,          &Bs[buf][boff]);                    \
    glds16(gB + 16 * K + k0_, &Bs[buf][boff + 16 * 32]);          \
    glds16(gB + 32 * K + k0_, &Bs[buf][boff + 32 * 32]);          \
    glds16(gB + 48 * K + k0_, &Bs[buf][boff + 48 * 32]);          \
  } while (0)

#define G_COMP(buf) do {                                                    \
    bf16x8 af[4], bfr[8];                                                   \
    _Pragma("unroll")                                                       \
    for (int i = 0; i < 4; i++)                                             \
      af[i] = *(const bf16x8*)(&As[buf][(wr + i * 16 + ln) * 32 + qsw]);    \
    _Pragma("unroll")                                                       \
    for (int j = 0; j < 8; j++)                                             \
      bfr[j] = *(const bf16x8*)(&Bs[buf][(wc + j * 16 + ln) * 32 + qsw]);   \
    _Pragma("unroll")                                                       \
    for (int i = 0; i < 4; i++)                                             \
      _Pragma("unroll")                                                     \
      for (int j = 0; j < 8; j++)                                           \
        acc[i][j] = __builtin_amdgcn_mfma_f32_16x16x32_bf16(af[i], bfr[j], acc[i][j], 0, 0, 0); \
  } while (0)

  const int nk = K >> 5;
  G_STAGE(0, 0); G_STAGE(1, 1); G_STAGE(2, 2);   // 18 loads in flight
  int cur = 0;
  for (int kt = 0; kt < nk; ++kt) {
    asm volatile("s_waitcnt vmcnt(12)" ::: "memory");  // buf[cur]'s 6 landed
    __builtin_amdgcn_sched_barrier(0);
    __builtin_amdgcn_s_barrier();
    asm volatile("" ::: "memory");
    G_COMP(cur);
    __builtin_amdgcn_sched_barrier(0);
    asm volatile("" ::: "memory");
    __builtin_amdgcn_s_barrier();                      // all reads done
    const int ks = (kt + 3 < nk) ? (kt + 3) : (nk - 1);
    G_STAGE(cur, ks);                                  // refill freed buffer
    cur = (cur == 2) ? 0 : cur + 1;
  }
#undef G_STAGE
#undef G_COMP

#pragma unroll
  for (int j = 0; j < 8; j++) {
    const int col = bn + wc + j * 16 + ln;
    float bv;
    if (MODE == 4) bv = (col < 1024) ? bias[col] : bias2[col - 1024];
    else           bv = bias[col];
#pragma unroll
    for (int i = 0; i < 4; i++) {
#pragma unroll
      for (int r = 0; r < 4; r++) {
        const int row = bm + wr + i * 16 + quad * 4 + r;
        float v = sanit(acc[i][j][r] + bv);
        if (MODE == 1) v = gelu_f(v);
        if (MODE == 3 && (col % 192) < 64) v *= SCL_L2E;
        ((__bf16*)Cout)[(size_t)row * N + col] = (__bf16)v;
      }
    }
  }
}

// ============================================================
// GEMM 128x128, 3-stage pipeline + XCD row-chunk + LDS XOR-swizzle.
// MODE 0: bf16 out; 1: gelu->bf16; 2: f32 out;
// MODE 3: qkv Q-col scale; 4: dual bias
// SPLIT=1: split-K over blockIdx.z (2 halves); partial z -> f32 at
// Cout + z*MROWS*N; bias added only by z==0. Consumer (ln_k) sums.
// ============================================================
template<int MODE, int SPLIT>
__global__ __launch_bounds__(256) void gemm_bt(
    const __bf16* __restrict__ A, const __bf16* __restrict__ Bt,
    const float* __restrict__ bias, const float* __restrict__ bias2,
    void* __restrict__ Cout, int N, int K)
{
  __shared__ __align__(16) __bf16 As[3][128 * 32];
  __shared__ __align__(16) __bf16 Bs[3][128 * 32];

  int bx, by;
  xcd_rowchunk(bx, by);
  const int bm = by * 128, bn = bx * 128;
  const int kz = SPLIT ? blockIdx.z : 0;
  const int kOff = SPLIT ? kz * (K >> 1) : 0;
  const int tid = threadIdx.x, wid = tid >> 6, lane = tid & 63;
  const int quad = lane >> 4, ln = lane & 15;

  const int sgc = ((lane & 3) ^ ((lane >> 3) & 3)) * 8;
  const __bf16* gA = A  + (size_t)(bm + wid * 32 + (lane >> 2)) * K + sgc + kOff;
  const __bf16* gB = Bt + (size_t)(bn + wid * 32 + (lane >> 2)) * K + sgc + kOff;
  const int soff = (wid * 32) * 32;
  const int qsw = (quad ^ ((ln >> 1) & 3)) * 8;

  f32x4 acc[4][4];
#pragma unroll
  for (int i = 0; i < 4; i++)
#pragma unroll
    for (int j = 0; j < 4; j++) acc[i][j] = (f32x4){0.f, 0.f, 0.f, 0.f};

  const int wr = (wid >> 1) * 64, wc = (wid & 1) * 64;

#define G_STAGE(buf, kt) do {                                     \
    const int k0_ = (kt) * 32;                                    \
    glds16(gA + k0_,          &As[buf][soff]);                    \
    glds16(gA + 16 * K + k0_, &As[buf][soff + 16 * 32]);          \
    glds16(gB + k0_,          &Bs[buf][soff]);                    \
    glds16(gB + 16 * K + k0_, &Bs[buf][soff + 16 * 32]);          \
  } while (0)

#define G_COMP(buf) do {                                                    \
    bf16x8 af[4], bfr[4];                                                   \
    _Pragma("unroll")                                                       \
    for (int i = 0; i < 4; i++)                                             \
      af[i] = *(const bf16x8*)(&As[buf][(wr + i * 16 + ln) * 32 + qsw]);    \
    _Pragma("unroll")                                                       \
    for (int j = 0; j < 4; j++)                                             \
      bfr[j] = *(const bf16x8*)(&Bs[buf][(wc + j * 16 + ln) * 32 + qsw]);   \
    _Pragma("unroll")                                                       \
    for (int i = 0; i < 4; i++)                                             \
      _Pragma("unroll")                                                     \
      for (int j = 0; j < 4; j++)                                           \
        acc[i][j] = __builtin_amdgcn_mfma_f32_16x16x32_bf16(af[i], bfr[j], acc[i][j], 0, 0, 0); \
  } while (0)

  const int nk = (K >> SPLIT) >> 5;
  G_STAGE(0, 0); G_STAGE(1, 1); G_STAGE(2, 2);
  int cur = 0;
  for (int kt = 0; kt < nk; ++kt) {
    asm volatile("s_waitcnt vmcnt(8)" ::: "memory");   // buf[cur]'s 4 landed
    __builtin_amdgcn_sched_barrier(0);
    __builtin_amdgcn_s_barrier();
    asm volatile("" ::: "memory");
    G_COMP(cur);
    __builtin_amdgcn_sched_barrier(0);
    asm volatile("" ::: "memory");
    __builtin_amdgcn_s_barrier();                      // all reads of buf[cur] done
    const int ks = (kt + 3 < nk) ? (kt + 3) : (nk - 1);
    G_STAGE(cur, ks);                                  // refill freed buffer
    cur = (cur == 2) ? 0 : cur + 1;
  }
#undef G_STAGE
#undef G_COMP

  float* outF = (float*)Cout + (SPLIT ? (size_t)kz * MROWS * N : 0);
#pragma unroll
  for (int j = 0; j < 4; j++) {
    const int col = bn + wc + j * 16 + ln;
    float bv;
    if (MODE == 4) bv = (col < 1024) ? bias[col] : bias2[col - 1024];
    else           bv = bias[col];
    if (SPLIT && kz) bv = 0.f;
#pragma unroll
    for (int i = 0; i < 4; i++) {
#pragma unroll
      for (int r = 0; r < 4; r++) {
        const int row = bm + wr + i * 16 + quad * 4 + r;
        float v = sanit(acc[i][j][r] + bv);
        if (MODE == 1) v = gelu_f(v);
        if (MODE == 3 && (col % 192) < 64) v *= SCL_L2E;
        if (MODE == 2) outF[(size_t)row * N + col] = v;
        else           ((__bf16*)Cout)[(size_t)row * N + col] = (__bf16)v;
      }
    }
  }
}

// ============================================================
// GEMM 128x64, 3-stage pipeline + XCD row-chunk + LDS XOR-swizzle.
// Used for the three N=1024 K=1024 projections.
// MODE 0: bf16; 2: f32; 3: bf16 scaled by SCL_L2E (cross-attn Q)
// ============================================================
template<int MODE>
__global__ __launch_bounds__(256) void gemm_bt64(
    const __bf16* __restrict__ A, const __bf16* __restrict__ Bt,
    const float* __restrict__ bias, void* __restrict__ Cout,
    int N, int K)
{
  __shared__ __align__(16) __bf16 As[3][128 * 32];
  __shared__ __align__(16) __bf16 Bs[3][64 * 32];

  int bx, by;
  xcd_rowchunk(bx, by);
  const int bm = by * 128, bn = bx * 64;
  const int tid = threadIdx.x, wid = tid >> 6, lane = tid & 63;
  const int quad = lane >> 4, ln = lane & 15;

  const int sgc = ((lane & 3) ^ ((lane >> 3) & 3)) * 8;
  const __bf16* gA = A  + (size_t)(bm + wid * 32 + (lane >> 2)) * K + sgc;
  const __bf16* gB = Bt + (size_t)(bn + wid * 16 + (lane >> 2)) * K + sgc;
  const int aoff = (wid * 32) * 32;
  const int boff = (wid * 16) * 32;
  const int qsw = (quad ^ ((ln >> 1) & 3)) * 8;

  f32x4 acc[4][2];
#pragma unroll
  for (int i = 0; i < 4; i++)
#pragma unroll
    for (int j = 0; j < 2; j++) acc[i][j] = (f32x4){0.f, 0.f, 0.f, 0.f};

  const int wr = (wid >> 1) * 64, wc = (wid & 1) * 32;

#define G_STAGE(buf, kt) do {                                     \
    const int k0_ = (kt) * 32;                                    \
    glds16(gA + k0_,          &As[buf][aoff]);                    \
    glds16(gA + 16 * K + k0_, &As[buf][aoff + 16 * 32]);          \
    glds16(gB + k0_,          &Bs[buf][boff]);                    \
  } while (0)

#define G_COMP(buf) do {                                                    \
    bf16x8 af[4], bfr[2];                                                   \
    _Pragma("unroll")                                                       \
    for (int i = 0; i < 4; i++)                                             \
      af[i] = *(const bf16x8*)(&As[buf][(wr + i * 16 + ln) * 32 + qsw]);    \
    _Pragma("unroll")                                                       \
    for (int j = 0; j < 2; j++)                                             \
      bfr[j] = *(const bf16x8*)(&Bs[buf][(wc + j * 16 + ln) * 32 + qsw]);   \
    _Pragma("unroll")                                                       \
    for (int i = 0; i < 4; i++)                                             \
      _Pragma("unroll")                                                     \
      for (int j = 0; j < 2; j++)                                           \
        acc[i][j] = __builtin_amdgcn_mfma_f32_16x16x32_bf16(af[i], bfr[j], acc[i][j], 0, 0, 0); \
  } while (0)

  const int nk = K >> 5;
  G_STAGE(0, 0); G_STAGE(1, 1); G_STAGE(2, 2);
  int cur = 0;
  for (int kt = 0; kt < nk; ++kt) {
    asm volatile("s_waitcnt vmcnt(6)" ::: "memory");   // buf[cur]'s 3 landed
    __builtin_amdgcn_sched_barrier(0);
    __builtin_amdgcn_s_barrier();
    asm volatile("" ::: "memory");
    G_COMP(cur);
    __builtin_amdgcn_sched_barrier(0);
    asm volatile("" ::: "memory");
    __builtin_amdgcn_s_barrier();                      // all reads done
    const int ks = (kt + 3 < nk) ? (kt + 3) : (nk - 1);
    G_STAGE(cur, ks);
    cur = (cur == 2) ? 0 : cur + 1;
  }
#undef G_STAGE
#undef G_COMP

#pragma unroll
  for (int j = 0; j < 2; j++) {
    const int col = bn + wc + j * 16 + ln;
    const float bv = bias[col];
#pragma unroll
    for (int i = 0; i < 4; i++) {
#pragma unroll
      for (int r = 0; r < 4; r++) {
        const int row = bm + wr + i * 16 + quad * 4 + r;
        float v = sanit(acc[i][j][r] + bv);
        if (MODE == 3) v *= SCL_L2E;
        if (MODE == 2) ((float*)Cout)[(size_t)row * N + col] = v;
        else           ((__bf16*)Cout)[(size_t)row * N + col] = (__bf16)v;
      }
    }
  }
}

// ============================================================
// Flash attention (R7 causal balance) + T5 setprio around MFMA
// clusters (attn regime: independent blocks at different phases).
// grid = 512; block 256. LDS 48 KB.
// ============================================================
__global__ __launch_bounds__(256) void attn(
    const __bf16* __restrict__ qp, int qStride, int qMul, int qAdd,
    const __bf16* __restrict__ kp, int kStride, int kMul, int kAdd,
    const __bf16* __restrict__ vt, __bf16* __restrict__ outp, int causal)
{
  __shared__ __align__(16) __bf16 Kt[2][64 * 64];   // [buf][row][64] swizzled
  __shared__ __align__(16) __bf16 Vt[2][64 * 64];   // [buf][dh][64]  swizzled
  __shared__ __align__(16) __bf16 ptl[4][32 * 64];  // per-wave P, swizzled

  const int id = blockIdx.x;
  const int bh = ((id >> 6) << 3) | (id & 7);       // keep bh%8 == id%8 (XCD)
  const int q0 = (id >> 3) & 7;
  const int qblk = ((id >> 8) & 1) ? (7 - q0) : q0; // complementary pairing
  const int b = bh >> 4, h = bh & 15;
  const int tid = threadIdx.x, wid = tid >> 6, lane = tid & 63;
  const int quad = lane >> 4, ln = lane & 15;
  const int qbase = qblk * 128;
  const int rowb0 = qbase + wid * 32;               // wave's first Q row
  const int rowTop = rowb0 + 31;

  // ---- Q fragments in registers: A[m=ln][k=quad*8+j] ----
  bf16x8 aq[2][2];
#pragma unroll
  for (int rf = 0; rf < 2; ++rf) {
    const __bf16* qr = qp + (size_t)(b * SS + rowb0 + rf * 16 + ln) * qStride
                          + h * qMul + qAdd;
#pragma unroll
    for (int ks = 0; ks < 2; ++ks)
      aq[rf][ks] = *(const bf16x8*)(qr + ks * 32 + quad * 8);
  }

  f32x4 acc[2][4];
#pragma unroll
  for (int rf = 0; rf < 2; ++rf)
#pragma unroll
    for (int nb = 0; nb < 4; ++nb) acc[rf][nb] = (f32x4){0.f, 0.f, 0.f, 0.f};
  float l_r[2][4] = {{0.f,0.f,0.f,0.f},{0.f,0.f,0.f,0.f}};

  const __bf16* kbase = kp + (size_t)(b * SS) * kStride + h * kMul + kAdd;
  const __bf16* vtb = vt + (size_t)bh * 64 * 1024;
  __bf16* ptw = ptl[wid];

  const int kvEnd = causal ? (qbase + 128) : SS;
  const int nT = kvEnd >> 6;

  const int sr = wid * 16 + (lane >> 3);   // +8 for p=1
  const int sq = lane & 7;

  // prologue: stage tile 0
#pragma unroll
  for (int p = 0; p < 2; ++p) {
    const int r = sr + p * 8;
    const int qs = (sq ^ (r & 7)) * 8;
    glds16(kbase + (size_t)r * kStride + qs, Kt[0] + (wid * 2 + p) * 512);
    glds16(vtb + (size_t)r * 1024 + qs,      Vt[0] + (wid * 2 + p) * 512);
  }

  for (int t = 0; t < nT; ++t) {
    const int cur = t & 1;
    const int kv0 = t * 64;

    if (t + 1 < nT) {
      const int kn = kv0 + 64;
#pragma unroll
      for (int p = 0; p < 2; ++p) {
        const int r = sr + p * 8;
        const int qs = (sq ^ (r & 7)) * 8;
        glds16(kbase + (size_t)(kn + r) * kStride + qs, Kt[cur ^ 1] + (wid * 2 + p) * 512);
        glds16(vtb + (size_t)r * 1024 + kn + qs,        Vt[cur ^ 1] + (wid * 2 + p) * 512);
      }
      __asm__ volatile("s_waitcnt vmcnt(4)" ::: "memory");  // tile t landed (mine)
    } else {
      __asm__ volatile("s_waitcnt vmcnt(0)" ::: "memory");
    }
    __builtin_amdgcn_sched_barrier(0);
    __builtin_amdgcn_s_barrier();              // everyone's quarter landed
    __asm__ volatile("" ::: "memory");
    __builtin_amdgcn_sched_barrier(0);

    if (!causal || kv0 <= rowTop) {
      const __bf16* kt = Kt[cur];
      const __bf16* vv = Vt[cur];

      // ---- QK^T: 16 MFMA, swizzled K reads ----
      f32x4 sc[2][4];
      {
        bf16x8 kf[4][2];
#pragma unroll
        for (int c = 0; c < 4; ++c) {
          const int row = c * 16 + ln;
#pragma unroll
          for (int ks = 0; ks < 2; ++ks)
            kf[c][ks] = *(const bf16x8*)(kt + row * 64 + (((ks * 4 + quad) ^ (ln & 7)) * 8));
        }
        __builtin_amdgcn_s_setprio(1);
#pragma unroll
        for (int rf = 0; rf < 2; ++rf)
#pragma unroll
          for (int c = 0; c < 4; ++c) {
            f32x4 s_ = (f32x4){0.f, 0.f, 0.f, 0.f};
            s_ = __builtin_amdgcn_mfma_f32_16x16x32_bf16(aq[rf][0], kf[c][0], s_, 0, 0, 0);
            s_ = __builtin_amdgcn_mfma_f32_16x16x32_bf16(aq[rf][1], kf[c][1], s_, 0, 0, 0);
            sc[rf][c] = s_;
          }
        __builtin_amdgcn_s_setprio(0);
      }

      // ---- softmax (Q pre-scaled -> bare exp2) + swizzled P write ----
#pragma unroll
      for (int rf = 0; rf < 2; ++rf) {
        const bool doMask = causal && (kv0 + 63 > rowb0 + rf * 16);
#pragma unroll
        for (int r = 0; r < 4; ++r) {
          const int rowg = rowb0 + rf * 16 + quad * 4 + r;
          float p[4];
#pragma unroll
          for (int c = 0; c < 4; ++c) {
            float e = sc[rf][c][r];
            if (doMask && (kv0 + c * 16 + ln > rowg)) e = NEG_BIG;
            p[c] = exp2f(e);
          }
          l_r[rf][r] += (p[0] + p[1]) + (p[2] + p[3]);
          const int m = rf * 16 + quad * 4 + r;
          __bf16* pr = ptw + m * 64;
#pragma unroll
          for (int c = 0; c < 4; ++c) {
            const int col = c * 16 + ln;
            pr[(((col >> 3) ^ (m & 7)) << 3) + (col & 7)] = (__bf16)p[c];
          }
        }
      }
      __asm__ volatile("s_waitcnt lgkmcnt(0)" ::: "memory");
      __builtin_amdgcn_sched_barrier(0);

      // ---- PV: 16 MFMA, swizzled P / V reads ----
      {
        bf16x8 pa[2][2];
#pragma unroll
        for (int rf = 0; rf < 2; ++rf) {
          const int m = rf * 16 + ln;
#pragma unroll
          for (int ks = 0; ks < 2; ++ks)
            pa[rf][ks] = *(const bf16x8*)(ptw + m * 64 + (((ks * 4 + quad) ^ (m & 7)) * 8));
        }
        __builtin_amdgcn_s_setprio(1);
#pragma unroll
        for (int nb = 0; nb < 4; ++nb) {
          const int vrow = nb * 16 + ln;
          const bf16x8 vf0 = *(const bf16x8*)(vv + vrow * 64 + (((quad)     ^ (ln & 7)) * 8));
          const bf16x8 vf1 = *(const bf16x8*)(vv + vrow * 64 + (((4 + quad) ^ (ln & 7)) * 8));
#pragma unroll
          for (int rf = 0; rf < 2; ++rf) {
            acc[rf][nb] = __builtin_amdgcn_mfma_f32_16x16x32_bf16(pa[rf][0], vf0, acc[rf][nb], 0, 0, 0);
            acc[rf][nb] = __builtin_amdgcn_mfma_f32_16x16x32_bf16(pa[rf][1], vf1, acc[rf][nb], 0, 0, 0);
          }
        }
        __builtin_amdgcn_s_setprio(0);
      }
    }

    __asm__ volatile("" ::: "memory");
    __builtin_amdgcn_sched_barrier(0);
    __builtin_amdgcn_s_barrier();              // buf[cur] free for next stage
  }

  // ---- finalize: row-sum over the 16 lanes of each ln group ----
#pragma unroll
  for (int rf = 0; rf < 2; ++rf) {
#pragma unroll
    for (int r = 0; r < 4; ++r) {
      float l = l_r[rf][r];
#pragma unroll
      for (int off = 1; off < 16; off <<= 1) l += __shfl_xor(l, off, 64);
      const float inv = 1.f / fmaxf(l, 1e-30f);
      const int rowg = rowb0 + rf * 16 + quad * 4 + r;
      __bf16* op = outp + (size_t)(b * SS + rowg) * DD + h * 64;
#pragma unroll
      for (int nb = 0; nb < 4; ++nb)
        op[nb * 16 + ln] = (__bf16)sanit(acc[rf][nb][r] * inv);
    }
  }
}

// ============================================================
// LayerNorm rows of 1024; optional second projection partial
// ============================================================
__global__ __launch_bounds__(256) void ln_k(
    const float* __restrict__ residf, const float* __restrict__ proj,
    const float* __restrict__ proj2,
    const float* __restrict__ g, const float* __restrict__ be,
    float* __restrict__ outf, __bf16* __restrict__ outb)
{
  const int row = blockIdx.x, tid = threadIdx.x;
  const f32x4 pb = ((const f32x4*)(proj   + (size_t)row * 1024))[tid];
  const f32x4 rb = ((const f32x4*)(residf + (size_t)row * 1024))[tid];
  f32x4 x;
#pragma unroll
  for (int i = 0; i < 4; i++) x[i] = pb[i] + rb[i];
  if (proj2) {
    const f32x4 qb_ = ((const f32x4*)(proj2 + (size_t)row * 1024))[tid];
#pragma unroll
    for (int i = 0; i < 4; i++) x[i] += qb_[i];
  }
#pragma unroll
  for (int i = 0; i < 4; i++)
    x[i] = fminf(fmaxf(x[i], -1e15f), 1e15f);
  float s  = x[0] + x[1] + x[2] + x[3];
  float ss = x[0]*x[0] + x[1]*x[1] + x[2]*x[2] + x[3]*x[3];
#pragma unroll
  for (int off = 1; off < 64; off <<= 1) {
    s  += __shfl_xor(s,  off, 64);
    ss += __shfl_xor(ss, off, 64);
  }
  __shared__ float sm[8];
  if ((tid & 63) == 0) { sm[tid >> 6] = s; sm[4 + (tid >> 6)] = ss; }
  __syncthreads();
  s  = sm[0] + sm[1] + sm[2] + sm[3];
  ss = sm[4] + sm[5] + sm[6] + sm[7];
  const float mean = s * (1.f / 1024.f);
  const float var  = fmaxf(ss * (1.f / 1024.f) - mean * mean, 0.f);
  const float rstd = rsqrtf(var + 1e-5f);
  const int c = tid * 4;
  f32x4 o;
#pragma unroll
  for (int i = 0; i < 4; i++)
    o[i] = g[c + i] * ((x[i] - mean) * rstd) + be[c + i];
  if (outf) ((f32x4*)(outf + (size_t)row * 1024))[tid] = o;
  if (outb) {
    bf16x4 ob;
#pragma unroll
    for (int i = 0; i < 4; i++) ob[i] = (__bf16)o[i];
    ((bf16x4*)(outb + (size_t)row * 1024))[tid] = ob;
  }
}

// ============================================================
extern "C" void kernel_launch(void* const* d_in, const int* in_sizes, int n_in,
                              void* d_out, int out_size, void* d_ws, size_t ws_size,
                              hipStream_t stream)
{
  const float* x      = (const float*)d_in[0];
  const float* enc    = (const float*)d_in[1];
  const float* w_qkv  = (const float*)d_in[2];
  const float* b_qkv  = (const float*)d_in[3];
  const float* w_sa_o = (const float*)d_in[4];
  const float* b_sa_o = (const float*)d_in[5];
  const float* w_q    = (const float*)d_in[6];
  const float* b_q    = (const float*)d_in[7];
  const float* w_k    = (const float*)d_in[8];
  const float* b_k    = (const float*)d_in[9];
  const float* w_v    = (const float*)d_in[10];
  const float* b_v    = (const float*)d_in[11];
  const float* w_ca_o = (const float*)d_in[12];
  const float* b_ca_o = (const float*)d_in[13];
  const float* w1     = (const float*)d_in[14];
  const float* b1     = (const float*)d_in[15];
  const float* w2     = (const float*)d_in[16];
  const float* b2     = (const float*)d_in[17];
  const float* g1     = (const float*)d_in[18];
  const float* be1    = (const float*)d_in[19];
  const float* g2     = (const float*)d_in[20];
  const float* be2    = (const float*)d_in[21];
  const float* g3     = (const float*)d_in[22];
  const float* be3    = (const float*)d_in[23];

  // ---- workspace layout, peak ~136 MB ----
  const size_t MB = 1024 * 1024;
  char* base = (char*)d_ws;
  __bf16* wqkvT = (__bf16*)(base + 0 * MB);
  __bf16* wsaoT = (__bf16*)(base + 6 * MB);
  __bf16* wqT   = (__bf16*)(base + 8 * MB);
  __bf16* wkvT  = (__bf16*)(base + 10 * MB);   // wkT (10-12) + wvT (12-14) contiguous
  __bf16* wkT   = (__bf16*)(base + 10 * MB);
  __bf16* wvT   = (__bf16*)(base + 12 * MB);
  __bf16* wcaoT = (__bf16*)(base + 14 * MB);
  __bf16* w1T   = (__bf16*)(base + 0 * MB);    // overlays small weights, post-CA
  __bf16* w2T   = (__bf16*)(base + 8 * MB);
  __bf16* xb    = (__bf16*)(base + 16 * MB);
  __bf16* encb  = (__bf16*)(base + 24 * MB);
  __bf16* qkv   = (__bf16*)(base + 32 * MB);   // 24 MB (self-attn fused qkv)
  __bf16* kvb   = (__bf16*)(base + 32 * MB);   // CA merged K|V [4096][2048], 16 MB
  __bf16* qcab  = (__bf16*)(base + 48 * MB);   // CA Q [4096][1024], 8 MB
  __bf16* vt    = (__bf16*)(base + 56 * MB);   // 8 MB
  __bf16* mid   = (__bf16*)(base + 32 * MB);   // overlays, FFN phase (32 MB)
  __bf16* attnb = (__bf16*)(base + 64 * MB);
  float*  proj  = (float*) (base + 72 * MB);   // 16 MB (FFN2 partial z=0)
  float*  h1f   = (float*) (base + 88 * MB);   // 16 MB
  __bf16* h1b   = (__bf16*)(base + 104 * MB);
  float*  h2f   = (float*) (base + 112 * MB);
  __bf16* h2b   = (__bf16*)(base + 128 * MB);
  (void)wkT; (void)wvT;

  // ---- input converts + early weight transposes ----
  cvt2_bf16<<<8192, 256, 0, stream>>>(x, xb, enc, encb);
  wtrans<<<dim3(48, 16), 256, 0, stream>>>(w_qkv, wqkvT, 1024, 3072);
  wtrans5<<<dim3(16, 80), 256, 0, stream>>>(w_sa_o, w_q, w_k, w_v, w_ca_o,
                                            wsaoT, wqT, wkT, wvT, wcaoT);

  // ---- self-attention (Q pre-scaled by 0.125*log2e in MODE 3) ----
  gemm_bt256<3><<<dim3(12, 32), 256, 0, stream>>>(xb, wqkvT, b_qkv, nullptr, qkv, 3072, 1024);
  vtrans<<<dim3(16, 64), 256, 0, stream>>>(qkv, 3072, 192, 128, vt);
  attn<<<512, 256, 0, stream>>>(qkv, 3072, 192, 0,
                                qkv, 3072, 192, 64, vt, attnb, 1);
  gemm_bt64<2><<<dim3(16, 32), 256, 0, stream>>>(attnb, wsaoT, b_sa_o, proj, 1024, 1024);
  ln_k<<<4096, 256, 0, stream>>>(x, proj, nullptr, g1, be1, h1f, h1b);

  // ---- cross-attention (K,V merged into one N=2048 GEMM) ----
  gemm_bt64<3><<<dim3(16, 32), 256, 0, stream>>>(h1b, wqT, b_q, qcab, 1024, 1024);
  gemm_bt256<4><<<dim3(8, 32), 256, 0, stream>>>(encb, wkvT, b_k, b_v, kvb, 2048, 1024);
  vtrans<<<dim3(16, 64), 256, 0, stream>>>(kvb, 2048, 64, 1024, vt);
  attn<<<512, 256, 0, stream>>>(qcab, 1024, 64, 0,
                                kvb, 2048, 64, 0, vt, attnb, 0);
  gemm_bt64<2><<<dim3(16, 32), 256, 0, stream>>>(attnb, wcaoT, b_ca_o, proj, 1024, 1024);
  ln_k<<<4096, 256, 0, stream>>>(h1f, proj, nullptr, g2, be2, h2f, h2b);

  // ---- FFN (FFN2: 128x128 tile + split-K=2, summed in final ln) ----
  wtrans<<<dim3(64, 16), 256, 0, stream>>>(w1, w1T, 1024, 4096);
  wtrans<<<dim3(16, 64), 256, 0, stream>>>(w2, w2T, 4096, 1024);
  gemm_bt256<1><<<dim3(16, 32), 256, 0, stream>>>(h2b, w1T, b1, nullptr, mid, 4096, 1024);
  gemm_bt<2, 1><<<dim3(8, 32, 2), 256, 0, stream>>>(mid, w2T, b2, nullptr, proj, 1024, 4096);
  ln_k<<<4096, 256, 0, stream>>>(h2f, proj, proj + (size_t)MROWS * 1024,
                                 g3, be3, (float*)d_out, nullptr);

  (void)in_sizes; (void)n_in; (void)out_size; (void)ws_size;
}

// Round 12
// 519.965 us; speedup vs baseline: 1.0407x; 1.0407x over previous
//
#include <hip/hip_runtime.h>

// ---- problem constants ----
#define BB 4
#define SS 1024
#define DD 1024
#define HH 16
#define DHH 64
#define DFF 4096
#define MROWS 4096   // B*S
#define NEG_BIG (-1e30f)
#define LOG2E 1.4426950408889634f
#define SCL_L2E 0.1803368801111244f   // 0.125 * log2(e)

typedef float  f32x4  __attribute__((ext_vector_type(4)));
typedef __bf16 bf16x8 __attribute__((ext_vector_type(8)));
typedef __bf16 bf16x4 __attribute__((ext_vector_type(4)));

#define DEV __device__ __forceinline__

DEV void glds16(const __bf16* g, __bf16* l) {
  __builtin_amdgcn_global_load_lds((__attribute__((address_space(1))) void*)(g),
                                   (__attribute__((address_space(3))) void*)(l),
                                   16, 0, 0);
}

DEV float sanit(float v) {  // NaN/inf absorbing clamp
  return fminf(fmaxf(v, -1e30f), 1e30f);
}

// exact-GELU via A&S 7.1.26 erf (|err|<=1.5e-7, invisible at bf16).
DEV float gelu_f(float v) {
  const float z  = fabsf(v) * 0.70710678118654752f;
  const float t  = __builtin_amdgcn_rcpf(1.f + 0.3275911f * z);
  float poly = ((((1.061405429f * t - 1.453152027f) * t + 1.421413741f) * t
                 - 0.284496736f) * t + 0.254829592f) * t;
  float er = 1.f - poly * __expf(-z * z);
  er = copysignf(er, v);
  return 0.5f * v * (1.f + er);
}

// XCD row-chunk swizzle (T1): hw id w runs on XCD w%8; logical
// idl = (w%8)*(nwg/8) + w/8 gives each XCD a CONTIGUOUS chunk of
// logical blocks; x-major decode -> chunks cover complete rows, so
// each A row-panel is fetched by exactly ONE XCD's L2.
DEV void xcd_rowchunk(int& bx, int& by) {
  const int gx = gridDim.x;
  const int nwg = gx * gridDim.y;
  const int id = blockIdx.x + gx * blockIdx.y;
  const int idl = (id & 7) * (nwg >> 3) + (id >> 3);
  bx = idl % gx;
  by = idl / gx;
}

// ============================================================
// f32 -> bf16 elementwise convert; handles x (4096 blks) then enc
// ============================================================
__global__ __launch_bounds__(256) void cvt2_bf16(
    const float* __restrict__ srcA, __bf16* __restrict__ dstA,
    const float* __restrict__ srcB, __bf16* __restrict__ dstB)
{
  const int bid = blockIdx.x;
  const float* src = (bid < 4096) ? srcA : srcB;
  __bf16* dst      = (bid < 4096) ? dstA : dstB;
  const int idx = ((bid < 4096) ? bid : (bid - 4096)) * 256 + threadIdx.x;
  const f32x4 v = ((const f32x4*)src)[idx];
  bf16x4 o;
#pragma unroll
  for (int i = 0; i < 4; i++) o[i] = (__bf16)v[i];
  ((bf16x4*)dst)[idx] = o;
}

// ============================================================
// LDS-tiled transpose+convert: src f32 [K][N] -> dst bf16 [N][K]
// ============================================================
__global__ __launch_bounds__(256) void wtrans(const float* __restrict__ src,
                                              __bf16* __restrict__ dst,
                                              int K, int N)
{
  __shared__ float t[64][65];
  const int k0 = blockIdx.y * 64, n0 = blockIdx.x * 64;
  const int c = threadIdx.x & 63, r0 = threadIdx.x >> 6;
#pragma unroll
  for (int i = 0; i < 16; i++) {
    const int r = r0 * 16 + i;
    t[r][c] = src[(size_t)(k0 + r) * N + n0 + c];
  }
  __syncthreads();
#pragma unroll
  for (int i = 0; i < 16; i++) {
    const int r = r0 * 16 + i;
    dst[(size_t)(n0 + r) * K + k0 + c] = (__bf16)t[c][r];
  }
}

// ============================================================
// Five 1024x1024 weight transposes in one launch; grid (16, 80)
// ============================================================
__global__ __launch_bounds__(256) void wtrans5(
    const float* __restrict__ s0, const float* __restrict__ s1,
    const float* __restrict__ s2, const float* __restrict__ s3,
    const float* __restrict__ s4,
    __bf16* __restrict__ d0, __bf16* __restrict__ d1,
    __bf16* __restrict__ d2, __bf16* __restrict__ d3,
    __bf16* __restrict__ d4)
{
  __shared__ float t[64][65];
  const int wi = blockIdx.y >> 4;
  const float* src = (wi == 0) ? s0 : (wi == 1) ? s1 : (wi == 2) ? s2
                   : (wi == 3) ? s3 : s4;
  __bf16* dst = (wi == 0) ? d0 : (wi == 1) ? d1 : (wi == 2) ? d2
              : (wi == 3) ? d3 : d4;
  const int k0 = (blockIdx.y & 15) * 64, n0 = blockIdx.x * 64;
  const int c = threadIdx.x & 63, r0 = threadIdx.x >> 6;
#pragma unroll
  for (int i = 0; i < 16; i++) {
    const int r = r0 * 16 + i;
    t[r][c] = src[(size_t)(k0 + r) * 1024 + n0 + c];
  }
  __syncthreads();
#pragma unroll
  for (int i = 0; i < 16; i++) {
    const int r = r0 * 16 + i;
    dst[(size_t)(n0 + r) * 1024 + k0 + c] = (__bf16)t[c][r];
  }
}

// ============================================================
// LDS-tiled V transpose (bf16): dst[bh][d][s]
// ============================================================
__global__ __launch_bounds__(256) void vtrans(const __bf16* __restrict__ src,
                                              int stride, int colMul, int colAdd,
                                              __bf16* __restrict__ dst)
{
  __shared__ __bf16 t[64][66];
  const int bh = blockIdx.y, b = bh >> 4, h = bh & 15;
  const int s0 = blockIdx.x * 64;
  const int c = threadIdx.x & 63, r0 = threadIdx.x >> 6;
  const __bf16* sp = src + (size_t)(b * SS) * stride + h * colMul + colAdd;
#pragma unroll
  for (int i = 0; i < 16; i++) {
    const int s = r0 * 16 + i;
    t[s][c] = sp[(size_t)(s0 + s) * stride + c];
  }
  __syncthreads();
  __bf16* dp = dst + (size_t)bh * 64 * 1024;
#pragma unroll
  for (int i = 0; i < 16; i++) {
    const int d = r0 * 16 + i;
    dp[(size_t)d * 1024 + s0 + c] = t[c][d];
  }
}

// ============================================================
// GEMM 128x256 (4 waves, 2Mx2N; per-wave 64x128 = acc[4][8]):
// 32 MFMA + 12 ds_read per K-iter per wave. 3-stage pipeline,
// vmcnt(12), XCD row-chunk, LDS XOR-swizzle. LDS 72 KB -> 2 blk/CU.
// Used only where grid = 512 (exactly 2/CU even): FFN1.
// MODE 1: gelu->bf16
// ============================================================
template<int MODE>
__global__ __launch_bounds__(256, 2) void gemm_bt256(
    const __bf16* __restrict__ A, const __bf16* __restrict__ Bt,
    const float* __restrict__ bias, const float* __restrict__ bias2,
    void* __restrict__ Cout, int N, int K)
{
  __shared__ __align__(16) __bf16 As[3][128 * 32];
  __shared__ __align__(16) __bf16 Bs[3][256 * 32];

  int bx, by;
  xcd_rowchunk(bx, by);
  const int bm = by * 128, bn = bx * 256;
  const int tid = threadIdx.x, wid = tid >> 6, lane = tid & 63;
  const int quad = lane >> 4, ln = lane & 15;

  const int sgc = ((lane & 3) ^ ((lane >> 3) & 3)) * 8;
  const __bf16* gA = A  + (size_t)(bm + wid * 32 + (lane >> 2)) * K + sgc;
  const __bf16* gB = Bt + (size_t)(bn + wid * 64 + (lane >> 2)) * K + sgc;
  const int aoff = (wid * 32) * 32;
  const int boff = (wid * 64) * 32;
  const int qsw = (quad ^ ((ln >> 1) & 3)) * 8;   // read-side swizzle

  f32x4 acc[4][8];
#pragma unroll
  for (int i = 0; i < 4; i++)
#pragma unroll
    for (int j = 0; j < 8; j++) acc[i][j] = (f32x4){0.f, 0.f, 0.f, 0.f};

  const int wr = (wid >> 1) * 64, wc = (wid & 1) * 128;

#define G_STAGE(buf, kt) do {                                     \
    const int k0_ = (kt) * 32;                                    \
    glds16(gA + k0_,          &As[buf][aoff]);                    \
    glds16(gA + 16 * K + k0_, &As[buf][aoff + 16 * 32]);          \
    glds16(gB + k0_,          &Bs[buf][boff]);                    \
    glds16(gB + 16 * K + k0_, &Bs[buf][boff + 16 * 32]);          \
    glds16(gB + 32 * K + k0_, &Bs[buf][boff + 32 * 32]);          \
    glds16(gB + 48 * K + k0_, &Bs[buf][boff + 48 * 32]);          \
  } while (0)

#define G_COMP(buf) do {                                                    \
    bf16x8 af[4], bfr[8];                                                   \
    _Pragma("unroll")                                                       \
    for (int i = 0; i < 4; i++)                                             \
      af[i] = *(const bf16x8*)(&As[buf][(wr + i * 16 + ln) * 32 + qsw]);    \
    _Pragma("unroll")                                                       \
    for (int j = 0; j < 8; j++)                                             \
      bfr[j] = *(const bf16x8*)(&Bs[buf][(wc + j * 16 + ln) * 32 + qsw]);   \
    _Pragma("unroll")                                                       \
    for (int i = 0; i < 4; i++)                                             \
      _Pragma("unroll")                                                     \
      for (int j = 0; j < 8; j++)                                           \
        acc[i][j] = __builtin_amdgcn_mfma_f32_16x16x32_bf16(af[i], bfr[j], acc[i][j], 0, 0, 0); \
  } while (0)

  const int nk = K >> 5;
  G_STAGE(0, 0); G_STAGE(1, 1); G_STAGE(2, 2);   // 18 loads in flight
  int cur = 0;
  for (int kt = 0; kt < nk; ++kt) {
    asm volatile("s_waitcnt vmcnt(12)" ::: "memory");  // buf[cur]'s 6 landed
    __builtin_amdgcn_sched_barrier(0);
    __builtin_amdgcn_s_barrier();
    asm volatile("" ::: "memory");
    G_COMP(cur);
    __builtin_amdgcn_sched_barrier(0);
    asm volatile("" ::: "memory");
    __builtin_amdgcn_s_barrier();                      // all reads done
    const int ks = (kt + 3 < nk) ? (kt + 3) : (nk - 1);
    G_STAGE(cur, ks);                                  // refill freed buffer
    cur = (cur == 2) ? 0 : cur + 1;
  }
#undef G_STAGE
#undef G_COMP

#pragma unroll
  for (int j = 0; j < 8; j++) {
    const int col = bn + wc + j * 16 + ln;
    float bv;
    if (MODE == 4) bv = (col < 1024) ? bias[col] : bias2[col - 1024];
    else           bv = bias[col];
#pragma unroll
    for (int i = 0; i < 4; i++) {
#pragma unroll
      for (int r = 0; r < 4; r++) {
        const int row = bm + wr + i * 16 + quad * 4 + r;
        float v = sanit(acc[i][j][r] + bv);
        if (MODE == 1) v = gelu_f(v);
        if (MODE == 3 && (col % 192) < 64) v *= SCL_L2E;
        ((__bf16*)Cout)[(size_t)row * N + col] = (__bf16)v;
      }
    }
  }
}

// ============================================================
// GEMM 128x128, 3-stage pipeline + XCD row-chunk + LDS XOR-swizzle.
// LDS 48 KB -> 3 blocks/CU.
// MODE 0: bf16 out; 1: gelu->bf16; 2: f32 out;
// MODE 3: qkv Q-col scale; 4: dual bias (merged KV)
// SPLIT=1: split-K over blockIdx.z (2 halves); partial z -> f32 at
// Cout + z*MROWS*N; bias added only by z==0. Consumer (ln_k) sums.
// ============================================================
template<int MODE, int SPLIT>
__global__ __launch_bounds__(256) void gemm_bt(
    const __bf16* __restrict__ A, const __bf16* __restrict__ Bt,
    const float* __restrict__ bias, const float* __restrict__ bias2,
    void* __restrict__ Cout, int N, int K)
{
  __shared__ __align__(16) __bf16 As[3][128 * 32];
  __shared__ __align__(16) __bf16 Bs[3][128 * 32];

  int bx, by;
  xcd_rowchunk(bx, by);
  const int bm = by * 128, bn = bx * 128;
  const int kz = SPLIT ? blockIdx.z : 0;
  const int kOff = SPLIT ? kz * (K >> 1) : 0;
  const int tid = threadIdx.x, wid = tid >> 6, lane = tid & 63;
  const int quad = lane >> 4, ln = lane & 15;

  const int sgc = ((lane & 3) ^ ((lane >> 3) & 3)) * 8;
  const __bf16* gA = A  + (size_t)(bm + wid * 32 + (lane >> 2)) * K + sgc + kOff;
  const __bf16* gB = Bt + (size_t)(bn + wid * 32 + (lane >> 2)) * K + sgc + kOff;
  const int soff = (wid * 32) * 32;
  const int qsw = (quad ^ ((ln >> 1) & 3)) * 8;

  f32x4 acc[4][4];
#pragma unroll
  for (int i = 0; i < 4; i++)
#pragma unroll
    for (int j = 0; j < 4; j++) acc[i][j] = (f32x4){0.f, 0.f, 0.f, 0.f};

  const int wr = (wid >> 1) * 64, wc = (wid & 1) * 64;

#define G_STAGE(buf, kt) do {                                     \
    const int k0_ = (kt) * 32;                                    \
    glds16(gA + k0_,          &As[buf][soff]);                    \
    glds16(gA + 16 * K + k0_, &As[buf][soff + 16 * 32]);          \
    glds16(gB + k0_,          &Bs[buf][soff]);                    \
    glds16(gB + 16 * K + k0_, &Bs[buf][soff + 16 * 32]);          \
  } while (0)

#define G_COMP(buf) do {                                                    \
    bf16x8 af[4], bfr[4];                                                   \
    _Pragma("unroll")                                                       \
    for (int i = 0; i < 4; i++)                                             \
      af[i] = *(const bf16x8*)(&As[buf][(wr + i * 16 + ln) * 32 + qsw]);    \
    _Pragma("unroll")                                                       \
    for (int j = 0; j < 4; j++)                                             \
      bfr[j] = *(const bf16x8*)(&Bs[buf][(wc + j * 16 + ln) * 32 + qsw]);   \
    _Pragma("unroll")                                                       \
    for (int i = 0; i < 4; i++)                                             \
      _Pragma("unroll")                                                     \
      for (int j = 0; j < 4; j++)                                           \
        acc[i][j] = __builtin_amdgcn_mfma_f32_16x16x32_bf16(af[i], bfr[j], acc[i][j], 0, 0, 0); \
  } while (0)

  const int nk = (K >> SPLIT) >> 5;
  G_STAGE(0, 0); G_STAGE(1, 1); G_STAGE(2, 2);
  int cur = 0;
  for (int kt = 0; kt < nk; ++kt) {
    asm volatile("s_waitcnt vmcnt(8)" ::: "memory");   // buf[cur]'s 4 landed
    __builtin_amdgcn_sched_barrier(0);
    __builtin_amdgcn_s_barrier();
    asm volatile("" ::: "memory");
    G_COMP(cur);
    __builtin_amdgcn_sched_barrier(0);
    asm volatile("" ::: "memory");
    __builtin_amdgcn_s_barrier();                      // all reads of buf[cur] done
    const int ks = (kt + 3 < nk) ? (kt + 3) : (nk - 1);
    G_STAGE(cur, ks);                                  // refill freed buffer
    cur = (cur == 2) ? 0 : cur + 1;
  }
#undef G_STAGE
#undef G_COMP

  float* outF = (float*)Cout + (SPLIT ? (size_t)kz * MROWS * N : 0);
#pragma unroll
  for (int j = 0; j < 4; j++) {
    const int col = bn + wc + j * 16 + ln;
    float bv;
    if (MODE == 4) bv = (col < 1024) ? bias[col] : bias2[col - 1024];
    else           bv = bias[col];
    if (SPLIT && kz) bv = 0.f;
#pragma unroll
    for (int i = 0; i < 4; i++) {
#pragma unroll
      for (int r = 0; r < 4; r++) {
        const int row = bm + wr + i * 16 + quad * 4 + r;
        float v = sanit(acc[i][j][r] + bv);
        if (MODE == 1) v = gelu_f(v);
        if (MODE == 3 && (col % 192) < 64) v *= SCL_L2E;
        if (MODE == 2) outF[(size_t)row * N + col] = v;
        else           ((__bf16*)Cout)[(size_t)row * N + col] = (__bf16)v;
      }
    }
  }
}

// ============================================================
// GEMM 128x64, 3-stage pipeline + XCD row-chunk + LDS XOR-swizzle.
// Used for the three N=1024 K=1024 projections.
// MODE 0: bf16; 2: f32; 3: bf16 scaled by SCL_L2E (cross-attn Q)
// ============================================================
template<int MODE>
__global__ __launch_bounds__(256) void gemm_bt64(
    const __bf16* __restrict__ A, const __bf16* __restrict__ Bt,
    const float* __restrict__ bias, void* __restrict__ Cout,
    int N, int K)
{
  __shared__ __align__(16) __bf16 As[3][128 * 32];
  __shared__ __align__(16) __bf16 Bs[3][64 * 32];

  int bx, by;
  xcd_rowchunk(bx, by);
  const int bm = by * 128, bn = bx * 64;
  const int tid = threadIdx.x, wid = tid >> 6, lane = tid & 63;
  const int quad = lane >> 4, ln = lane & 15;

  const int sgc = ((lane & 3) ^ ((lane >> 3) & 3)) * 8;
  const __bf16* gA = A  + (size_t)(bm + wid * 32 + (lane >> 2)) * K + sgc;
  const __bf16* gB = Bt + (size_t)(bn + wid * 16 + (lane >> 2)) * K + sgc;
  const int aoff = (wid * 32) * 32;
  const int boff = (wid * 16) * 32;
  const int qsw = (quad ^ ((ln >> 1) & 3)) * 8;

  f32x4 acc[4][2];
#pragma unroll
  for (int i = 0; i < 4; i++)
#pragma unroll
    for (int j = 0; j < 2; j++) acc[i][j] = (f32x4){0.f, 0.f, 0.f, 0.f};

  const int wr = (wid >> 1) * 64, wc = (wid & 1) * 32;

#define G_STAGE(buf, kt) do {                                     \
    const int k0_ = (kt) * 32;                                    \
    glds16(gA + k0_,          &As[buf][aoff]);                    \
    glds16(gA + 16 * K + k0_, &As[buf][aoff + 16 * 32]);          \
    glds16(gB + k0_,          &Bs[buf][boff]);                    \
  } while (0)

#define G_COMP(buf) do {                                                    \
    bf16x8 af[4], bfr[2];                                                   \
    _Pragma("unroll")                                                       \
    for (int i = 0; i < 4; i++)                                             \
      af[i] = *(const bf16x8*)(&As[buf][(wr + i * 16 + ln) * 32 + qsw]);    \
    _Pragma("unroll")                                                       \
    for (int j = 0; j < 2; j++)                                             \
      bfr[j] = *(const bf16x8*)(&Bs[buf][(wc + j * 16 + ln) * 32 + qsw]);   \
    _Pragma("unroll")                                                       \
    for (int i = 0; i < 4; i++)                                             \
      _Pragma("unroll")                                                     \
      for (int j = 0; j < 2; j++)                                           \
        acc[i][j] = __builtin_amdgcn_mfma_f32_16x16x32_bf16(af[i], bfr[j], acc[i][j], 0, 0, 0); \
  } while (0)

  const int nk = K >> 5;
  G_STAGE(0, 0); G_STAGE(1, 1); G_STAGE(2, 2);
  int cur = 0;
  for (int kt = 0; kt < nk; ++kt) {
    asm volatile("s_waitcnt vmcnt(6)" ::: "memory");   // buf[cur]'s 3 landed
    __builtin_amdgcn_sched_barrier(0);
    __builtin_amdgcn_s_barrier();
    asm volatile("" ::: "memory");
    G_COMP(cur);
    __builtin_amdgcn_sched_barrier(0);
    asm volatile("" ::: "memory");
    __builtin_amdgcn_s_barrier();                      // all reads done
    const int ks = (kt + 3 < nk) ? (kt + 3) : (nk - 1);
    G_STAGE(cur, ks);
    cur = (cur == 2) ? 0 : cur + 1;
  }
#undef G_STAGE
#undef G_COMP

#pragma unroll
  for (int j = 0; j < 2; j++) {
    const int col = bn + wc + j * 16 + ln;
    const float bv = bias[col];
#pragma unroll
    for (int i = 0; i < 4; i++) {
#pragma unroll
      for (int r = 0; r < 4; r++) {
        const int row = bm + wr + i * 16 + quad * 4 + r;
        float v = sanit(acc[i][j][r] + bv);
        if (MODE == 3) v *= SCL_L2E;
        if (MODE == 2) ((float*)Cout)[(size_t)row * N + col] = v;
        else           ((__bf16*)Cout)[(size_t)row * N + col] = (__bf16)v;
      }
    }
  }
}

// ============================================================
// Flash attention (R7 causal balance) + T5 setprio around MFMA
// clusters. grid = 512; block 256. LDS 48 KB.
// ============================================================
__global__ __launch_bounds__(256) void attn(
    const __bf16* __restrict__ qp, int qStride, int qMul, int qAdd,
    const __bf16* __restrict__ kp, int kStride, int kMul, int kAdd,
    const __bf16* __restrict__ vt, __bf16* __restrict__ outp, int causal)
{
  __shared__ __align__(16) __bf16 Kt[2][64 * 64];   // [buf][row][64] swizzled
  __shared__ __align__(16) __bf16 Vt[2][64 * 64];   // [buf][dh][64]  swizzled
  __shared__ __align__(16) __bf16 ptl[4][32 * 64];  // per-wave P, swizzled

  const int id = blockIdx.x;
  const int bh = ((id >> 6) << 3) | (id & 7);       // keep bh%8 == id%8 (XCD)
  const int q0 = (id >> 3) & 7;
  const int qblk = ((id >> 8) & 1) ? (7 - q0) : q0; // complementary pairing
  const int b = bh >> 4, h = bh & 15;
  const int tid = threadIdx.x, wid = tid >> 6, lane = tid & 63;
  const int quad = lane >> 4, ln = lane & 15;
  const int qbase = qblk * 128;
  const int rowb0 = qbase + wid * 32;               // wave's first Q row
  const int rowTop = rowb0 + 31;

  // ---- Q fragments in registers: A[m=ln][k=quad*8+j] ----
  bf16x8 aq[2][2];
#pragma unroll
  for (int rf = 0; rf < 2; ++rf) {
    const __bf16* qr = qp + (size_t)(b * SS + rowb0 + rf * 16 + ln) * qStride
                          + h * qMul + qAdd;
#pragma unroll
    for (int ks = 0; ks < 2; ++ks)
      aq[rf][ks] = *(const bf16x8*)(qr + ks * 32 + quad * 8);
  }

  f32x4 acc[2][4];
#pragma unroll
  for (int rf = 0; rf < 2; ++rf)
#pragma unroll
    for (int nb = 0; nb < 4; ++nb) acc[rf][nb] = (f32x4){0.f, 0.f, 0.f, 0.f};
  float l_r[2][4] = {{0.f,0.f,0.f,0.f},{0.f,0.f,0.f,0.f}};

  const __bf16* kbase = kp + (size_t)(b * SS) * kStride + h * kMul + kAdd;
  const __bf16* vtb = vt + (size_t)bh * 64 * 1024;
  __bf16* ptw = ptl[wid];

  const int kvEnd = causal ? (qbase + 128) : SS;
  const int nT = kvEnd >> 6;

  const int sr = wid * 16 + (lane >> 3);   // +8 for p=1
  const int sq = lane & 7;

  // prologue: stage tile 0
#pragma unroll
  for (int p = 0; p < 2; ++p) {
    const int r = sr + p * 8;
    const int qs = (sq ^ (r & 7)) * 8;
    glds16(kbase + (size_t)r * kStride + qs, Kt[0] + (wid * 2 + p) * 512);
    glds16(vtb + (size_t)r * 1024 + qs,      Vt[0] + (wid * 2 + p) * 512);
  }

  for (int t = 0; t < nT; ++t) {
    const int cur = t & 1;
    const int kv0 = t * 64;

    if (t + 1 < nT) {
      const int kn = kv0 + 64;
#pragma unroll
      for (int p = 0; p < 2; ++p) {
        const int r = sr + p * 8;
        const int qs = (sq ^ (r & 7)) * 8;
        glds16(kbase + (size_t)(kn + r) * kStride + qs, Kt[cur ^ 1] + (wid * 2 + p) * 512);
        glds16(vtb + (size_t)r * 1024 + kn + qs,        Vt[cur ^ 1] + (wid * 2 + p) * 512);
      }
      __asm__ volatile("s_waitcnt vmcnt(4)" ::: "memory");  // tile t landed (mine)
    } else {
      __asm__ volatile("s_waitcnt vmcnt(0)" ::: "memory");
    }
    __builtin_amdgcn_sched_barrier(0);
    __builtin_amdgcn_s_barrier();              // everyone's quarter landed
    __asm__ volatile("" ::: "memory");
    __builtin_amdgcn_sched_barrier(0);

    if (!causal || kv0 <= rowTop) {
      const __bf16* kt = Kt[cur];
      const __bf16* vv = Vt[cur];

      // ---- QK^T: 16 MFMA, swizzled K reads ----
      f32x4 sc[2][4];
      {
        bf16x8 kf[4][2];
#pragma unroll
        for (int c = 0; c < 4; ++c) {
          const int row = c * 16 + ln;
#pragma unroll
          for (int ks = 0; ks < 2; ++ks)
            kf[c][ks] = *(const bf16x8*)(kt + row * 64 + (((ks * 4 + quad) ^ (ln & 7)) * 8));
        }
        __builtin_amdgcn_s_setprio(1);
#pragma unroll
        for (int rf = 0; rf < 2; ++rf)
#pragma unroll
          for (int c = 0; c < 4; ++c) {
            f32x4 s_ = (f32x4){0.f, 0.f, 0.f, 0.f};
            s_ = __builtin_amdgcn_mfma_f32_16x16x32_bf16(aq[rf][0], kf[c][0], s_, 0, 0, 0);
            s_ = __builtin_amdgcn_mfma_f32_16x16x32_bf16(aq[rf][1], kf[c][1], s_, 0, 0, 0);
            sc[rf][c] = s_;
          }
        __builtin_amdgcn_s_setprio(0);
      }

      // ---- softmax (Q pre-scaled -> bare exp2) + swizzled P write ----
#pragma unroll
      for (int rf = 0; rf < 2; ++rf) {
        const bool doMask = causal && (kv0 + 63 > rowb0 + rf * 16);
#pragma unroll
        for (int r = 0; r < 4; ++r) {
          const int rowg = rowb0 + rf * 16 + quad * 4 + r;
          float p[4];
#pragma unroll
          for (int c = 0; c < 4; ++c) {
            float e = sc[rf][c][r];
            if (doMask && (kv0 + c * 16 + ln > rowg)) e = NEG_BIG;
            p[c] = exp2f(e);
          }
          l_r[rf][r] += (p[0] + p[1]) + (p[2] + p[3]);
          const int m = rf * 16 + quad * 4 + r;
          __bf16* pr = ptw + m * 64;
#pragma unroll
          for (int c = 0; c < 4; ++c) {
            const int col = c * 16 + ln;
            pr[(((col >> 3) ^ (m & 7)) << 3) + (col & 7)] = (__bf16)p[c];
          }
        }
      }
      __asm__ volatile("s_waitcnt lgkmcnt(0)" ::: "memory");
      __builtin_amdgcn_sched_barrier(0);

      // ---- PV: 16 MFMA, swizzled P / V reads ----
      {
        bf16x8 pa[2][2];
#pragma unroll
        for (int rf = 0; rf < 2; ++rf) {
          const int m = rf * 16 + ln;
#pragma unroll
          for (int ks = 0; ks < 2; ++ks)
            pa[rf][ks] = *(const bf16x8*)(ptw + m * 64 + (((ks * 4 + quad) ^ (m & 7)) * 8));
        }
        __builtin_amdgcn_s_setprio(1);
#pragma unroll
        for (int nb = 0; nb < 4; ++nb) {
          const int vrow = nb * 16 + ln;
          const bf16x8 vf0 = *(const bf16x8*)(vv + vrow * 64 + (((quad)     ^ (ln & 7)) * 8));
          const bf16x8 vf1 = *(const bf16x8*)(vv + vrow * 64 + (((4 + quad) ^ (ln & 7)) * 8));
#pragma unroll
          for (int rf = 0; rf < 2; ++rf) {
            acc[rf][nb] = __builtin_amdgcn_mfma_f32_16x16x32_bf16(pa[rf][0], vf0, acc[rf][nb], 0, 0, 0);
            acc[rf][nb] = __builtin_amdgcn_mfma_f32_16x16x32_bf16(pa[rf][1], vf1, acc[rf][nb], 0, 0, 0);
          }
        }
        __builtin_amdgcn_s_setprio(0);
      }
    }

    __asm__ volatile("" ::: "memory");
    __builtin_amdgcn_sched_barrier(0);
    __builtin_amdgcn_s_barrier();              // buf[cur] free for next stage
  }

  // ---- finalize: row-sum over the 16 lanes of each ln group ----
#pragma unroll
  for (int rf = 0; rf < 2; ++rf) {
#pragma unroll
    for (int r = 0; r < 4; ++r) {
      float l = l_r[rf][r];
#pragma unroll
      for (int off = 1; off < 16; off <<= 1) l += __shfl_xor(l, off, 64);
      const float inv = 1.f / fmaxf(l, 1e-30f);
      const int rowg = rowb0 + rf * 16 + quad * 4 + r;
      __bf16* op = outp + (size_t)(b * SS + rowg) * DD + h * 64;
#pragma unroll
      for (int nb = 0; nb < 4; ++nb)
        op[nb * 16 + ln] = (__bf16)sanit(acc[rf][nb][r] * inv);
    }
  }
}

// ============================================================
// LayerNorm rows of 1024; optional second projection partial
// ============================================================
__global__ __launch_bounds__(256) void ln_k(
    const float* __restrict__ residf, const float* __restrict__ proj,
    const float* __restrict__ proj2,
    const float* __restrict__ g, const float* __restrict__ be,
    float* __restrict__ outf, __bf16* __restrict__ outb)
{
  const int row = blockIdx.x, tid = threadIdx.x;
  const f32x4 pb = ((const f32x4*)(proj   + (size_t)row * 1024))[tid];
  const f32x4 rb = ((const f32x4*)(residf + (size_t)row * 1024))[tid];
  f32x4 x;
#pragma unroll
  for (int i = 0; i < 4; i++) x[i] = pb[i] + rb[i];
  if (proj2) {
    const f32x4 qb_ = ((const f32x4*)(proj2 + (size_t)row * 1024))[tid];
#pragma unroll
    for (int i = 0; i < 4; i++) x[i] += qb_[i];
  }
#pragma unroll
  for (int i = 0; i < 4; i++)
    x[i] = fminf(fmaxf(x[i], -1e15f), 1e15f);
  float s  = x[0] + x[1] + x[2] + x[3];
  float ss = x[0]*x[0] + x[1]*x[1] + x[2]*x[2] + x[3]*x[3];
#pragma unroll
  for (int off = 1; off < 64; off <<= 1) {
    s  += __shfl_xor(s,  off, 64);
    ss += __shfl_xor(ss, off, 64);
  }
  __shared__ float sm[8];
  if ((tid & 63) == 0) { sm[tid >> 6] = s; sm[4 + (tid >> 6)] = ss; }
  __syncthreads();
  s  = sm[0] + sm[1] + sm[2] + sm[3];
  ss = sm[4] + sm[5] + sm[6] + sm[7];
  const float mean = s * (1.f / 1024.f);
  const float var  = fmaxf(ss * (1.f / 1024.f) - mean * mean, 0.f);
  const float rstd = rsqrtf(var + 1e-5f);
  const int c = tid * 4;
  f32x4 o;
#pragma unroll
  for (int i = 0; i < 4; i++)
    o[i] = g[c + i] * ((x[i] - mean) * rstd) + be[c + i];
  if (outf) ((f32x4*)(outf + (size_t)row * 1024))[tid] = o;
  if (outb) {
    bf16x4 ob;
#pragma unroll
    for (int i = 0; i < 4; i++) ob[i] = (__bf16)o[i];
    ((bf16x4*)(outb + (size_t)row * 1024))[tid] = ob;
  }
}

// ============================================================
extern "C" void kernel_launch(void* const* d_in, const int* in_sizes, int n_in,
                              void* d_out, int out_size, void* d_ws, size_t ws_size,
                              hipStream_t stream)
{
  const float* x      = (const float*)d_in[0];
  const float* enc    = (const float*)d_in[1];
  const float* w_qkv  = (const float*)d_in[2];
  const float* b_qkv  = (const float*)d_in[3];
  const float* w_sa_o = (const float*)d_in[4];
  const float* b_sa_o = (const float*)d_in[5];
  const float* w_q    = (const float*)d_in[6];
  const float* b_q    = (const float*)d_in[7];
  const float* w_k    = (const float*)d_in[8];
  const float* b_k    = (const float*)d_in[9];
  const float* w_v    = (const float*)d_in[10];
  const float* b_v    = (const float*)d_in[11];
  const float* w_ca_o = (const float*)d_in[12];
  const float* b_ca_o = (const float*)d_in[13];
  const float* w1     = (const float*)d_in[14];
  const float* b1     = (const float*)d_in[15];
  const float* w2     = (const float*)d_in[16];
  const float* b2     = (const float*)d_in[17];
  const float* g1     = (const float*)d_in[18];
  const float* be1    = (const float*)d_in[19];
  const float* g2     = (const float*)d_in[20];
  const float* be2    = (const float*)d_in[21];
  const float* g3     = (const float*)d_in[22];
  const float* be3    = (const float*)d_in[23];

  // ---- workspace layout, peak ~136 MB ----
  const size_t MB = 1024 * 1024;
  char* base = (char*)d_ws;
  __bf16* wqkvT = (__bf16*)(base + 0 * MB);
  __bf16* wsaoT = (__bf16*)(base + 6 * MB);
  __bf16* wqT   = (__bf16*)(base + 8 * MB);
  __bf16* wkvT  = (__bf16*)(base + 10 * MB);   // wkT (10-12) + wvT (12-14) contiguous
  __bf16* wkT   = (__bf16*)(base + 10 * MB);
  __bf16* wvT   = (__bf16*)(base + 12 * MB);
  __bf16* wcaoT = (__bf16*)(base + 14 * MB);
  __bf16* w1T   = (__bf16*)(base + 0 * MB);    // overlays small weights, post-CA
  __bf16* w2T   = (__bf16*)(base + 8 * MB);
  __bf16* xb    = (__bf16*)(base + 16 * MB);
  __bf16* encb  = (__bf16*)(base + 24 * MB);
  __bf16* qkv   = (__bf16*)(base + 32 * MB);   // 24 MB (self-attn fused qkv)
  __bf16* kvb   = (__bf16*)(base + 32 * MB);   // CA merged K|V [4096][2048], 16 MB
  __bf16* qcab  = (__bf16*)(base + 48 * MB);   // CA Q [4096][1024], 8 MB
  __bf16* vt    = (__bf16*)(base + 56 * MB);   // 8 MB
  __bf16* mid   = (__bf16*)(base + 32 * MB);   // overlays, FFN phase (32 MB)
  __bf16* attnb = (__bf16*)(base + 64 * MB);
  float*  proj  = (float*) (base + 72 * MB);   // 16 MB (FFN2 partial z=0)
  float*  h1f   = (float*) (base + 88 * MB);   // 16 MB
  __bf16* h1b   = (__bf16*)(base + 104 * MB);
  float*  h2f   = (float*) (base + 112 * MB);
  __bf16* h2b   = (__bf16*)(base + 128 * MB);
  (void)wkT; (void)wvT;

  // ---- input converts + early weight transposes ----
  cvt2_bf16<<<8192, 256, 0, stream>>>(x, xb, enc, encb);
  wtrans<<<dim3(48, 16), 256, 0, stream>>>(w_qkv, wqkvT, 1024, 3072);
  wtrans5<<<dim3(16, 80), 256, 0, stream>>>(w_sa_o, w_q, w_k, w_v, w_ca_o,
                                            wsaoT, wqT, wkT, wvT, wcaoT);

  // ---- self-attention (Q pre-scaled by 0.125*log2e in MODE 3) ----
  // qkv on 128x128: grid 768 = exactly 3 blocks/CU (even; bt256's 384
  // blocks = 1.5/CU was imbalanced)
  gemm_bt<3, 0><<<dim3(24, 32), 256, 0, stream>>>(xb, wqkvT, b_qkv, nullptr, qkv, 3072, 1024);
  vtrans<<<dim3(16, 64), 256, 0, stream>>>(qkv, 3072, 192, 128, vt);
  attn<<<512, 256, 0, stream>>>(qkv, 3072, 192, 0,
                                qkv, 3072, 192, 64, vt, attnb, 1);
  gemm_bt64<2><<<dim3(16, 32), 256, 0, stream>>>(attnb, wsaoT, b_sa_o, proj, 1024, 1024);
  ln_k<<<4096, 256, 0, stream>>>(x, proj, nullptr, g1, be1, h1f, h1b);

  // ---- cross-attention (K,V merged; 128x128: grid 512 = 2/CU even,
  // 8 waves/CU vs bt256's 256 blocks = 1/CU with no cross-block TLP) ----
  gemm_bt64<3><<<dim3(16, 32), 256, 0, stream>>>(h1b, wqT, b_q, qcab, 1024, 1024);
  gemm_bt<4, 0><<<dim3(16, 32), 256, 0, stream>>>(encb, wkvT, b_k, b_v, kvb, 2048, 1024);
  vtrans<<<dim3(16, 64), 256, 0, stream>>>(kvb, 2048, 64, 1024, vt);
  attn<<<512, 256, 0, stream>>>(qcab, 1024, 64, 0,
                                kvb, 2048, 64, 0, vt, attnb, 0);
  gemm_bt64<2><<<dim3(16, 32), 256, 0, stream>>>(attnb, wcaoT, b_ca_o, proj, 1024, 1024);
  ln_k<<<4096, 256, 0, stream>>>(h1f, proj, nullptr, g2, be2, h2f, h2b);

  // ---- FFN (FFN1 on bt256 @512=2/CU even; FFN2 128x128 split-K=2) ----
  wtrans<<<dim3(64, 16), 256, 0, stream>>>(w1, w1T, 1024, 4096);
  wtrans<<<dim3(16, 64), 256, 0, stream>>>(w2, w2T, 4096, 1024);
  gemm_bt256<1><<<dim3(16, 32), 256, 0, stream>>>(h2b, w1T, b1, nullptr, mid, 4096, 1024);
  gemm_bt<2, 1><<<dim3(8, 32, 2), 256, 0, stream>>>(mid, w2T, b2, nullptr, proj, 1024, 4096);
  ln_k<<<4096, 256, 0, stream>>>(h2f, proj, proj + (size_t)MROWS * 1024,
                                 g3, be3, (float*)d_out, nullptr);

  (void)in_sizes; (void)n_in; (void)out_size; (void)ws_size;
}